// Round 25
// baseline (248.144 us; speedup 1.0000x reference)
//
#include <hip/hip_runtime.h>
#include <hip/hip_bf16.h>

typedef unsigned short u16;
typedef unsigned int   u32;
typedef __bf16 bf16x8 __attribute__((ext_vector_type(8)));
typedef float  f32x4  __attribute__((ext_vector_type(4)));
typedef u16    u16x8  __attribute__((ext_vector_type(8)));
typedef u32    u32x2  __attribute__((ext_vector_type(2)));

#define GAS __attribute__((address_space(1)))
#define LAS __attribute__((address_space(3)))

__device__ __forceinline__ void gload_lds16(const void* g, void* lds) {
  __builtin_amdgcn_global_load_lds((GAS u32*)g, (LAS u32*)lds, 16, 0, 0);
}

__device__ __forceinline__ u16 f2bf(float f) {
  union { float f; u32 u; } v; v.f = f;
  u32 r = v.u + 0x7FFFu + ((v.u >> 16) & 1u);   // round-to-nearest-even
  return (u16)(r >> 16);
}

__device__ __forceinline__ u32 cvtpk_bf16(float lo, float hi) {
  u32 r;
  asm("v_cvt_pk_bf16_f32 %0, %1, %2" : "=v"(r) : "v"(lo), "v"(hi));
  return r;
}

template <int N> __device__ __forceinline__ void wait_vmcnt() {
  if constexpr (N == 3)      asm volatile("s_waitcnt vmcnt(3)" ::: "memory");
  else if constexpr (N == 4) asm volatile("s_waitcnt vmcnt(4)" ::: "memory");
  else if constexpr (N == 8) asm volatile("s_waitcnt vmcnt(8)" ::: "memory");
  else                       asm volatile("s_waitcnt vmcnt(0)" ::: "memory");
}

// ---------------- elementwise cast x: f32 -> bf16 (8 elems/thread) ----------------
__global__ __launch_bounds__(256) void cast_x_kernel(const float* __restrict__ x,
                                                     u16* __restrict__ xb) {
  int i = (blockIdx.x * 256 + threadIdx.x) * 8;
  float4 a = *(const float4*)(x + i);
  float4 b = *(const float4*)(x + i + 4);
  u16x8 o;
  o[0] = f2bf(a.x); o[1] = f2bf(a.y); o[2] = f2bf(a.z); o[3] = f2bf(a.w);
  o[4] = f2bf(b.x); o[5] = f2bf(b.y); o[6] = f2bf(b.z); o[7] = f2bf(b.w);
  *(u16x8*)(xb + i) = o;
}

// ------------- fused transpose-cast: 4x W[k][n] f32 -> WT[n][k] bf16 (x scale) ----
struct TC4 {
  const float* W[4];
  u16* D[4];
  float s[4];
};
__global__ __launch_bounds__(256) void transcast4(TC4 p) {
  __shared__ float t[32][33];
  const int tx = threadIdx.x, ty = threadIdx.y;      // 32 x 8
  const int z = blockIdx.z;
  const float* __restrict__ W = p.W[z];
  u16* __restrict__ WT = p.D[z];
  const float scale = p.s[z];
  const int c0 = blockIdx.x * 32, r0 = blockIdx.y * 32;
#pragma unroll
  for (int i = 0; i < 4; ++i)
    t[ty + i * 8][tx] = W[(r0 + ty + i * 8) * 2048 + c0 + tx];
  __syncthreads();
#pragma unroll
  for (int i = 0; i < 4; ++i)
    WT[(c0 + ty + i * 8) * 2048 + r0 + tx] = f2bf(t[tx][ty + i * 8] * scale);
}

// ---------------- GEMM BMxBN, BK=64, 8 waves, 2-barrier/tile pipeline -------------
// R24 schedule (passed). This round: MFMA operands SWAPPED (mfma(bfr, af)) so
// the accumulator holds D^T fragments: lane owns m = r15, n = g*4 + r with FOUR
// CONSECUTIVE n per lane -> epilogue vectorizes (bf16: 8B u32x2 stores via
// cvt_pk; f32: 16B f32x4 stores + vector bias). Same values to same addresses;
// LDS reads / MFMA count / staging byte-identical. tau keeps r-contiguity:
// for n = base + r (r<4), tau(n&31) = const + r, 8B-aligned.
template <int OUTF32, int PERMN, int BM, int BN, int WM, int WN>
__global__ __launch_bounds__(512, 2) void gemm256(
    const u16* __restrict__ A, const u16* __restrict__ B,
    float* __restrict__ Cf, u16* __restrict__ Cb, const float* __restrict__ bias,
    int M, int N, int K, int lda, int ldb, int ldc) {
  constexpr int PM = BM / WM, PN = BN / WN;    // per-wave output
  constexpr int MI = PM / 16, NI = PN / 16;    // acc tile counts
  constexpr int CA = BM / 128, CB = BN / 128;  // staging chunks per thread
  __shared__ alignas(16) u16 lds[2][2][(BM + BN) * 32];

  const int tid = threadIdx.x;                 // 0..511
  const int lane = tid & 63, wave = tid >> 6;
  const int wm = wave / WN, wn = wave % WN;
  const int r15 = lane & 15, g = lane >> 4;

  const int gx = gridDim.x;
  const int nwg = gx * gridDim.y;
  const int orig = blockIdx.y * gx + blockIdx.x;
  const int wg = (orig & 7) * (nwg >> 3) + (orig >> 3);
  const int tm = (wg % gx) * BM, tn = (wg / gx) * BN;

  int aoff[CA], boff[CB];
#pragma unroll
  for (int i = 0; i < CA; ++i) {
    int c = i * 512 + tid, row = c >> 2, ch = c & 3;
    aoff[i] = (tm + row) * lda + (ch ^ ((row >> 1) & 3)) * 8;
  }
#pragma unroll
  for (int i = 0; i < CB; ++i) {
    int c = i * 512 + tid, row = c >> 2, ch = c & 3;
    boff[i] = (tn + row) * ldb + (ch ^ ((row >> 1) & 3)) * 8;
  }

  auto stageA = [&](int kofs, int buf, int ks) {
#pragma unroll
    for (int i = 0; i < CA; ++i)
      gload_lds16(A + aoff[i] + kofs,
                  (char*)&lds[buf][ks][0] + (i * 8 + wave) * 1024);
  };
  auto stageB = [&](int kofs, int buf, int ks) {
#pragma unroll
    for (int i = 0; i < CB; ++i)
      gload_lds16(B + boff[i] + kofs,
                  (char*)&lds[buf][ks][BM * 32] + (i * 8 + wave) * 1024);
  };

  f32x4 acc[MI][NI] = {};
  const int NT = K / 64;
  const int fsw = (r15 >> 1) & 3;              // fragment-read chunk swizzle

  // prologue: stage tile 0 completely
  stageA(0, 0, 0);  stageB(0, 0, 0);
  stageA(32, 0, 1); stageB(32, 0, 1);

  for (int t = 0; t < NT; ++t) {
    const int cur = t & 1, nxt = cur ^ 1;
    const int kn = (t + 1 < NT) ? (t + 1) * 64 : 0;   // last tile: dummy restage

    wait_vmcnt<0>();                           // drains exactly tile t's loads
    __builtin_amdgcn_s_barrier();              // tile t published; t-1 reads done
    __builtin_amdgcn_sched_barrier(0);

    // issue ALL of tile t+1's stages now (full tile of compute to land)
    stageA(kn, nxt, 0);  stageB(kn, nxt, 0);
    stageA(kn + 32, nxt, 1); stageB(kn + 32, nxt, 1);

#pragma unroll
    for (int ks = 0; ks < 2; ++ks) {
      const char* Ab = (const char*)&lds[cur][ks][0];
      const char* Bb = (const char*)&lds[cur][ks][BM * 32];
      bf16x8 bfr[NI], af[MI];
#pragma unroll
      for (int ni = 0; ni < NI; ++ni)
        bfr[ni] = *(const bf16x8*)(Bb + (wn * PN + ni * 16 + r15) * 64 +
                                   ((g ^ fsw) << 4));
#pragma unroll
      for (int mi = 0; mi < MI; ++mi)
        af[mi] = *(const bf16x8*)(Ab + (wm * PM + mi * 16 + r15) * 64 +
                                  ((g ^ fsw) << 4));

      __builtin_amdgcn_s_setprio(1);
#pragma unroll
      for (int mi = 0; mi < MI; ++mi)
#pragma unroll
        for (int ni = 0; ni < NI; ++ni)
          acc[mi][ni] = __builtin_amdgcn_mfma_f32_16x16x32_bf16(bfr[ni], af[mi],
                                                                acc[mi][ni], 0, 0, 0);
      __builtin_amdgcn_s_setprio(0);
    }

    __builtin_amdgcn_s_barrier();              // all waves done reading buf[cur]
  }

  // epilogue: D^T fragments -> lane owns m = r15-row, n = 4 consecutive cols
#pragma unroll
  for (int mi = 0; mi < MI; ++mi) {
    const int m = tm + wm * PM + mi * 16 + r15;
#pragma unroll
    for (int ni = 0; ni < NI; ++ni) {
      int nb = tn + wn * PN + ni * 16 + g * 4;       // base of 4 consecutive n
      if (PERMN) {
        int k = nb & 31;   // r-contiguity preserved: (k>>2),(k>>4) indep of r
        nb = (nb & ~31) | (8 * ((k >> 2) & 3) + 4 * ((k >> 4) & 1) + (k & 3));
      }
      if (OUTF32) {
        f32x4 bv = *(const f32x4*)(bias + nb);
        f32x4 v;
#pragma unroll
        for (int r = 0; r < 4; ++r) v[r] = acc[mi][ni][r] + bv[r];
        *(f32x4*)(Cf + (size_t)m * ldc + nb) = v;
      } else {
        u32x2 pv;
        pv[0] = cvtpk_bf16(acc[mi][ni][0], acc[mi][ni][1]);
        pv[1] = cvtpk_bf16(acc[mi][ni][2], acc[mi][ni][3]);
        *(u32x2*)(Cb + (size_t)m * ldc + nb) = pv;
      }
    }
  }
}

// ---------------- flash attention: 4 waves x 2 q-strips, fixed-shift softmax ------
// (exact R23/R24 state — passed at ~80 us. DO NOT TOUCH.)
__global__ __launch_bounds__(256, 2) void attn_kernel(const u16* __restrict__ QK,
                                                      const u16* __restrict__ VtG,
                                                      u16* __restrict__ O) {
  __shared__ alignas(16) u16 Ks[2][64 * 128];   // 16KB each
  __shared__ alignas(16) u16 Vs[2][128 * 64];   // 16KB each

  const int tid = threadIdx.x, lane = tid & 63, wave = tid >> 6;  // wave 0..3
  const int r15 = lane & 15, g = lane >> 4;

  const int orig = (blockIdx.z * 16 + blockIdx.y) * 16 + blockIdx.x;  // 512 wgs
  const int wg = (orig & 7) * 64 + (orig >> 3);
  const int qb = wg & 15, h = (wg >> 4) & 15, b = wg >> 8;

  const u16* Qp = QK + (size_t)b * 2048 * 4096 + h * 128;
  const u16* Kp = Qp + 2048;
  const u16* Vp = VtG + (size_t)(h * 128) * 4096 + b * 2048;

  const int qrow0 = qb * 128 + wave * 32 + r15;
  bf16x8 qf[2][4];
#pragma unroll
  for (int s = 0; s < 2; ++s)
#pragma unroll
    for (int kc = 0; kc < 4; ++kc)
      qf[s][kc] = *(const bf16x8*)(Qp + (size_t)(qrow0 + s * 16) * 4096 +
                                   kc * 32 + g * 8);
  asm volatile("s_waitcnt vmcnt(0)" ::: "memory");

  int koff[4], voff[4];
#pragma unroll
  for (int i = 0; i < 4; ++i) {
    int c = i * 256 + tid;                     // 0..1023
    int kr = c >> 4, kj = c & 15;
    koff[i] = kr * 4096 + (kj ^ (kr & 7)) * 8;
    int vr = c >> 3, vj = c & 7;
    voff[i] = vr * 4096 + (vj ^ (vr & 7)) * 8;
  }
  const int sw = r15 & 7;
  const float M0 = 12.0f;                      // fixed softmax shift (log2 units)

  f32x4 oacc[2][8] = {};
  float l[2] = {0.f, 0.f};                     // per-lane partials (16 kv/lane)

#pragma unroll
  for (int i = 0; i < 4; ++i) {
    gload_lds16(Kp + koff[i], (char*)Ks[0] + (i * 4 + wave) * 1024);
    gload_lds16(Vp + voff[i], (char*)Vs[0] + (i * 4 + wave) * 1024);
  }

  for (int t = 0; t < 32; ++t) {
    const int cur = t & 1;
    if (t < 31) {
      const size_t kv0n = (size_t)(t + 1) * 64;
#pragma unroll
      for (int i = 0; i < 4; ++i) {
        gload_lds16(Kp + kv0n * 4096 + koff[i], (char*)Ks[cur ^ 1] + (i * 4 + wave) * 1024);
        gload_lds16(Vp + kv0n + voff[i], (char*)Vs[cur ^ 1] + (i * 4 + wave) * 1024);
      }
      wait_vmcnt<8>();                         // drain tile t's 8, keep t+1 in flight
    } else {
      wait_vmcnt<0>();
    }
    __builtin_amdgcn_s_barrier();
    __builtin_amdgcn_sched_barrier(0);

    f32x4 sacc[2][4] = {};
    __builtin_amdgcn_s_setprio(1);
#pragma unroll
    for (int tt = 0; tt < 4; ++tt) {
      const int krow = tt * 16 + r15;
#pragma unroll
      for (int kc = 0; kc < 4; ++kc) {
        bf16x8 kf = *(const bf16x8*)((const char*)Ks[cur] + krow * 256 +
                                     (((kc * 4 + g) ^ sw) << 4));
        sacc[0][tt] = __builtin_amdgcn_mfma_f32_16x16x32_bf16(kf, qf[0][kc], sacc[0][tt], 0, 0, 0);
        sacc[1][tt] = __builtin_amdgcn_mfma_f32_16x16x32_bf16(kf, qf[1][kc], sacc[1][tt], 0, 0, 0);
      }
    }
    __builtin_amdgcn_s_setprio(0);

    // fixed-shift softmax: no cross-lane ops, no branches
    u32 pk[2][4][2];
#pragma unroll
    for (int s = 0; s < 2; ++s) {
      float rs = 0.f;
#pragma unroll
      for (int tt = 0; tt < 4; ++tt)
#pragma unroll
        for (int w = 0; w < 2; ++w) {
          float p0 = __builtin_amdgcn_exp2f(sacc[s][tt][2 * w] - M0);
          float p1 = __builtin_amdgcn_exp2f(sacc[s][tt][2 * w + 1] - M0);
          rs += p0 + p1;
          pk[s][tt][w] = cvtpk_bf16(p0, p1);
        }
      l[s] += rs;
    }

    __builtin_amdgcn_s_setprio(1);
#pragma unroll
    for (int dt = 0; dt < 8; ++dt) {
      const int d = dt * 16 + r15;
      const char* vrow = (const char*)Vs[cur] + d * 128;
      const int vsw = d & 7;
#pragma unroll
      for (int kh = 0; kh < 2; ++kh) {
        union { u32 u4[4]; bf16x8 v; } af, b0, b1;
        af.v = *(const bf16x8*)(vrow + (((4 * kh + g) ^ vsw) << 4));
        b0.u4[0] = pk[0][2 * kh][0];     b0.u4[1] = pk[0][2 * kh][1];
        b0.u4[2] = pk[0][2 * kh + 1][0]; b0.u4[3] = pk[0][2 * kh + 1][1];
        b1.u4[0] = pk[1][2 * kh][0];     b1.u4[1] = pk[1][2 * kh][1];
        b1.u4[2] = pk[1][2 * kh + 1][0]; b1.u4[3] = pk[1][2 * kh + 1][1];
        oacc[0][dt] = __builtin_amdgcn_mfma_f32_16x16x32_bf16(af.v, b0.v, oacc[0][dt], 0, 0, 0);
        oacc[1][dt] = __builtin_amdgcn_mfma_f32_16x16x32_bf16(af.v, b1.v, oacc[1][dt], 0, 0, 0);
      }
    }
    __builtin_amdgcn_s_setprio(0);

    __builtin_amdgcn_s_barrier();              // all waves done with buf[cur]
  }

  // epilogue: combine the 4 per-lane l partials once, then normalize and store
#pragma unroll
  for (int s = 0; s < 2; ++s) {
    float lt = l[s] + __shfl_xor(l[s], 16);
    lt += __shfl_xor(lt, 32);
    const float inv = 1.0f / lt;
    u16* Ob = O + ((size_t)(b * 2048 + qrow0 + s * 16)) * 2048 + h * 128;
#pragma unroll
    for (int dt = 0; dt < 8; ++dt) {
      u32x2 pair;
      pair[0] = cvtpk_bf16(oacc[s][dt][0] * inv, oacc[s][dt][1] * inv);
      pair[1] = cvtpk_bf16(oacc[s][dt][2] * inv, oacc[s][dt][3] * inv);
      *(u32x2*)(Ob + dt * 16 + 4 * g) = pair;
    }
  }
}

// ---------------- host ----------------
extern "C" void kernel_launch(void* const* d_in, const int* in_sizes, int n_in,
                              void* d_out, int out_size, void* d_ws, size_t ws_size,
                              hipStream_t stream) {
  const float* x  = (const float*)d_in[0];
  const float* Wq = (const float*)d_in[1];
  const float* Wk = (const float*)d_in[2];
  const float* Wv = (const float*)d_in[3];
  const float* Wo = (const float*)d_in[4];
  const float* bo = (const float*)d_in[5];
  float* out = (float*)d_out;

  char* ws = (char*)d_ws;
  u16* xb    = (u16*)ws;                               // 16 MiB (reused as attn O)
  u16* WqkvT = (u16*)(ws + (size_t)16 * 1024 * 1024);  // 24 MiB [6144][2048]
  u16* WoT   = (u16*)(ws + (size_t)40 * 1024 * 1024);  // 8 MiB  [2048][2048]
  u16* QK    = (u16*)(ws + (size_t)48 * 1024 * 1024);  // 32 MiB [4096][4096]
  u16* VtG   = (u16*)(ws + (size_t)80 * 1024 * 1024);  // 16 MiB [2048][4096]
  u16* Oattn = xb;

  const float C2 = 0.12753102f;   // (1/sqrt(128)) * log2(e), folded into Wk

  cast_x_kernel<<<4096, 256, 0, stream>>>(x, xb);

  TC4 p;
  p.W[0] = Wq; p.W[1] = Wk; p.W[2] = Wv; p.W[3] = Wo;
  p.D[0] = WqkvT;
  p.D[1] = WqkvT + (size_t)2048 * 2048;
  p.D[2] = WqkvT + (size_t)4096 * 2048;
  p.D[3] = WoT;
  p.s[0] = 1.0f; p.s[1] = C2; p.s[2] = 1.0f; p.s[3] = 1.0f;
  transcast4<<<dim3(64, 64, 4), dim3(32, 8), 0, stream>>>(p);

  // QK = xb @ [Wq|Wk_scaled]   (M=4096, N=4096, K=2048), 256x256 tiles, 256 wgs
  gemm256<0, 0, 256, 256, 2, 4><<<dim3(16, 16), 512, 0, stream>>>(
      xb, WqkvT, nullptr, QK, nullptr, 4096, 4096, 2048, 2048, 2048, 4096);
  // V^T = Wv^T @ x^T    (M=2048, N=4096, K=2048), 128x256 tiles, kv tau-permuted
  gemm256<0, 1, 128, 256, 2, 4><<<dim3(16, 16), 512, 0, stream>>>(
      WqkvT + (size_t)4096 * 2048, xb, nullptr, VtG, nullptr,
      2048, 4096, 2048, 2048, 2048, 4096);
  // attention: 128 q-rows per block, 512 blocks of 256 threads (2 strips/wave)
  attn_kernel<<<dim3(16, 16, 2), 256, 0, stream>>>(QK, VtG, Oattn);
  // out = O @ Wo + bo   (M=4096, N=2048, K=2048), 256x128 tiles, 256 wgs
  gemm256<1, 0, 256, 128, 4, 2><<<dim3(16, 16), 512, 0, stream>>>(
      Oattn, WoT, out, nullptr, bo, 4096, 2048, 2048, 2048, 2048, 2048);
}

// Round 26
// 244.803 us; speedup vs baseline: 1.0136x; 1.0136x over previous
//
#include <hip/hip_runtime.h>
#include <hip/hip_bf16.h>

typedef unsigned short u16;
typedef unsigned int   u32;
typedef __bf16 bf16x8 __attribute__((ext_vector_type(8)));
typedef float  f32x4  __attribute__((ext_vector_type(4)));
typedef u16    u16x8  __attribute__((ext_vector_type(8)));
typedef u32    u32x2  __attribute__((ext_vector_type(2)));

#define GAS __attribute__((address_space(1)))
#define LAS __attribute__((address_space(3)))

__device__ __forceinline__ void gload_lds16(const void* g, void* lds) {
  __builtin_amdgcn_global_load_lds((GAS u32*)g, (LAS u32*)lds, 16, 0, 0);
}

__device__ __forceinline__ u16 f2bf(float f) {
  union { float f; u32 u; } v; v.f = f;
  u32 r = v.u + 0x7FFFu + ((v.u >> 16) & 1u);   // round-to-nearest-even
  return (u16)(r >> 16);
}

__device__ __forceinline__ u32 cvtpk_bf16(float lo, float hi) {
  u32 r;
  asm("v_cvt_pk_bf16_f32 %0, %1, %2" : "=v"(r) : "v"(lo), "v"(hi));
  return r;
}

template <int N> __device__ __forceinline__ void wait_vmcnt() {
  if constexpr (N == 3)      asm volatile("s_waitcnt vmcnt(3)" ::: "memory");
  else if constexpr (N == 4) asm volatile("s_waitcnt vmcnt(4)" ::: "memory");
  else if constexpr (N == 8) asm volatile("s_waitcnt vmcnt(8)" ::: "memory");
  else                       asm volatile("s_waitcnt vmcnt(0)" ::: "memory");
}

// ---------------- elementwise cast x: f32 -> bf16 (8 elems/thread) ----------------
__global__ __launch_bounds__(256) void cast_x_kernel(const float* __restrict__ x,
                                                     u16* __restrict__ xb) {
  int i = (blockIdx.x * 256 + threadIdx.x) * 8;
  float4 a = *(const float4*)(x + i);
  float4 b = *(const float4*)(x + i + 4);
  u16x8 o;
  o[0] = f2bf(a.x); o[1] = f2bf(a.y); o[2] = f2bf(a.z); o[3] = f2bf(a.w);
  o[4] = f2bf(b.x); o[5] = f2bf(b.y); o[6] = f2bf(b.z); o[7] = f2bf(b.w);
  *(u16x8*)(xb + i) = o;
}

// ------------- fused transpose-cast: 4x W[k][n] f32 -> WT[n][k] bf16 (x scale) ----
struct TC4 {
  const float* W[4];
  u16* D[4];
  float s[4];
};
__global__ __launch_bounds__(256) void transcast4(TC4 p) {
  __shared__ float t[32][33];
  const int tx = threadIdx.x, ty = threadIdx.y;      // 32 x 8
  const int z = blockIdx.z;
  const float* __restrict__ W = p.W[z];
  u16* __restrict__ WT = p.D[z];
  const float scale = p.s[z];
  const int c0 = blockIdx.x * 32, r0 = blockIdx.y * 32;
#pragma unroll
  for (int i = 0; i < 4; ++i)
    t[ty + i * 8][tx] = W[(r0 + ty + i * 8) * 2048 + c0 + tx];
  __syncthreads();
#pragma unroll
  for (int i = 0; i < 4; ++i)
    WT[(c0 + ty + i * 8) * 2048 + r0 + tx] = f2bf(t[tx][ty + i * 8] * scale);
}

// ---------------- GEMM BMxBN, BK=64, 8 waves, 2-barrier/tile pipeline -------------
// Best-measured configuration (R24, 245.0 us total). Per K-tile: {vmcnt(0)
// [prefetch for t+1 not yet issued -> drains only tile t's loads]; barrier;
// issue all of t+1's stages; read+MFMA ks0 then ks1 (compiler interleaves via
// fine-grained lgkmcnt); barrier}. Two-barrier dbuf discipline, both-sides chunk
// swizzle, setprio on MFMA clusters. PERMN: tau-permute output cols within
// 32-groups (Vt GEMM) so the attn PV A-fragment is one contiguous b128.
template <int OUTF32, int PERMN, int BM, int BN, int WM, int WN>
__global__ __launch_bounds__(512, 2) void gemm256(
    const u16* __restrict__ A, const u16* __restrict__ B,
    float* __restrict__ Cf, u16* __restrict__ Cb, const float* __restrict__ bias,
    int M, int N, int K, int lda, int ldb, int ldc) {
  constexpr int PM = BM / WM, PN = BN / WN;    // per-wave output
  constexpr int MI = PM / 16, NI = PN / 16;    // acc tile counts
  constexpr int CA = BM / 128, CB = BN / 128;  // staging chunks per thread
  __shared__ alignas(16) u16 lds[2][2][(BM + BN) * 32];

  const int tid = threadIdx.x;                 // 0..511
  const int lane = tid & 63, wave = tid >> 6;
  const int wm = wave / WN, wn = wave % WN;
  const int r15 = lane & 15, g = lane >> 4;

  const int gx = gridDim.x;
  const int nwg = gx * gridDim.y;
  const int orig = blockIdx.y * gx + blockIdx.x;
  const int wg = (orig & 7) * (nwg >> 3) + (orig >> 3);
  const int tm = (wg % gx) * BM, tn = (wg / gx) * BN;

  int aoff[CA], boff[CB];
#pragma unroll
  for (int i = 0; i < CA; ++i) {
    int c = i * 512 + tid, row = c >> 2, ch = c & 3;
    aoff[i] = (tm + row) * lda + (ch ^ ((row >> 1) & 3)) * 8;
  }
#pragma unroll
  for (int i = 0; i < CB; ++i) {
    int c = i * 512 + tid, row = c >> 2, ch = c & 3;
    boff[i] = (tn + row) * ldb + (ch ^ ((row >> 1) & 3)) * 8;
  }

  auto stageA = [&](int kofs, int buf, int ks) {
#pragma unroll
    for (int i = 0; i < CA; ++i)
      gload_lds16(A + aoff[i] + kofs,
                  (char*)&lds[buf][ks][0] + (i * 8 + wave) * 1024);
  };
  auto stageB = [&](int kofs, int buf, int ks) {
#pragma unroll
    for (int i = 0; i < CB; ++i)
      gload_lds16(B + boff[i] + kofs,
                  (char*)&lds[buf][ks][BM * 32] + (i * 8 + wave) * 1024);
  };

  f32x4 acc[MI][NI] = {};
  const int NT = K / 64;
  const int fsw = (r15 >> 1) & 3;              // fragment-read chunk swizzle

  // prologue: stage tile 0 completely
  stageA(0, 0, 0);  stageB(0, 0, 0);
  stageA(32, 0, 1); stageB(32, 0, 1);

  for (int t = 0; t < NT; ++t) {
    const int cur = t & 1, nxt = cur ^ 1;
    const int kn = (t + 1 < NT) ? (t + 1) * 64 : 0;   // last tile: dummy restage

    wait_vmcnt<0>();                           // drains exactly tile t's loads
    __builtin_amdgcn_s_barrier();              // tile t published; t-1 reads done
    __builtin_amdgcn_sched_barrier(0);

    // issue ALL of tile t+1's stages now (full tile of compute to land)
    stageA(kn, nxt, 0);  stageB(kn, nxt, 0);
    stageA(kn + 32, nxt, 1); stageB(kn + 32, nxt, 1);

#pragma unroll
    for (int ks = 0; ks < 2; ++ks) {
      const char* Ab = (const char*)&lds[cur][ks][0];
      const char* Bb = (const char*)&lds[cur][ks][BM * 32];
      bf16x8 bfr[NI], af[MI];
#pragma unroll
      for (int ni = 0; ni < NI; ++ni)
        bfr[ni] = *(const bf16x8*)(Bb + (wn * PN + ni * 16 + r15) * 64 +
                                   ((g ^ fsw) << 4));
#pragma unroll
      for (int mi = 0; mi < MI; ++mi)
        af[mi] = *(const bf16x8*)(Ab + (wm * PM + mi * 16 + r15) * 64 +
                                  ((g ^ fsw) << 4));

      __builtin_amdgcn_s_setprio(1);
#pragma unroll
      for (int mi = 0; mi < MI; ++mi)
#pragma unroll
        for (int ni = 0; ni < NI; ++ni)
          acc[mi][ni] = __builtin_amdgcn_mfma_f32_16x16x32_bf16(af[mi], bfr[ni],
                                                                acc[mi][ni], 0, 0, 0);
      __builtin_amdgcn_s_setprio(0);
    }

    __builtin_amdgcn_s_barrier();              // all waves done reading buf[cur]
  }

  // epilogue
#pragma unroll
  for (int mi = 0; mi < MI; ++mi)
#pragma unroll
    for (int ni = 0; ni < NI; ++ni)
#pragma unroll
      for (int r = 0; r < 4; ++r) {
        int m = tm + wm * PM + mi * 16 + g * 4 + r;
        int n = tn + wn * PN + ni * 16 + r15;
        if (PERMN)
          n = (n & ~31) | (8 * ((n >> 2) & 3) + 4 * ((n >> 4) & 1) + (n & 3));
        float v = acc[mi][ni][r];
        if (OUTF32) Cf[(size_t)m * ldc + n] = v + bias[n];
        else        Cb[(size_t)m * ldc + n] = f2bf(v);
      }
}

// ---------------- flash attention: 4 waves x 2 q-strips, fixed-shift softmax ------
// (exact R23/R24 state — passed at ~80 us.)
__global__ __launch_bounds__(256, 2) void attn_kernel(const u16* __restrict__ QK,
                                                      const u16* __restrict__ VtG,
                                                      u16* __restrict__ O) {
  __shared__ alignas(16) u16 Ks[2][64 * 128];   // 16KB each
  __shared__ alignas(16) u16 Vs[2][128 * 64];   // 16KB each

  const int tid = threadIdx.x, lane = tid & 63, wave = tid >> 6;  // wave 0..3
  const int r15 = lane & 15, g = lane >> 4;

  const int orig = (blockIdx.z * 16 + blockIdx.y) * 16 + blockIdx.x;  // 512 wgs
  const int wg = (orig & 7) * 64 + (orig >> 3);
  const int qb = wg & 15, h = (wg >> 4) & 15, b = wg >> 8;

  const u16* Qp = QK + (size_t)b * 2048 * 4096 + h * 128;
  const u16* Kp = Qp + 2048;
  const u16* Vp = VtG + (size_t)(h * 128) * 4096 + b * 2048;

  const int qrow0 = qb * 128 + wave * 32 + r15;
  bf16x8 qf[2][4];
#pragma unroll
  for (int s = 0; s < 2; ++s)
#pragma unroll
    for (int kc = 0; kc < 4; ++kc)
      qf[s][kc] = *(const bf16x8*)(Qp + (size_t)(qrow0 + s * 16) * 4096 +
                                   kc * 32 + g * 8);
  asm volatile("s_waitcnt vmcnt(0)" ::: "memory");

  int koff[4], voff[4];
#pragma unroll
  for (int i = 0; i < 4; ++i) {
    int c = i * 256 + tid;                     // 0..1023
    int kr = c >> 4, kj = c & 15;
    koff[i] = kr * 4096 + (kj ^ (kr & 7)) * 8;
    int vr = c >> 3, vj = c & 7;
    voff[i] = vr * 4096 + (vj ^ (vr & 7)) * 8;
  }
  const int sw = r15 & 7;
  const float M0 = 12.0f;                      // fixed softmax shift (log2 units)

  f32x4 oacc[2][8] = {};
  float l[2] = {0.f, 0.f};                     // per-lane partials (16 kv/lane)

#pragma unroll
  for (int i = 0; i < 4; ++i) {
    gload_lds16(Kp + koff[i], (char*)Ks[0] + (i * 4 + wave) * 1024);
    gload_lds16(Vp + voff[i], (char*)Vs[0] + (i * 4 + wave) * 1024);
  }

  for (int t = 0; t < 32; ++t) {
    const int cur = t & 1;
    if (t < 31) {
      const size_t kv0n = (size_t)(t + 1) * 64;
#pragma unroll
      for (int i = 0; i < 4; ++i) {
        gload_lds16(Kp + kv0n * 4096 + koff[i], (char*)Ks[cur ^ 1] + (i * 4 + wave) * 1024);
        gload_lds16(Vp + kv0n + voff[i], (char*)Vs[cur ^ 1] + (i * 4 + wave) * 1024);
      }
      wait_vmcnt<8>();                         // drain tile t's 8, keep t+1 in flight
    } else {
      wait_vmcnt<0>();
    }
    __builtin_amdgcn_s_barrier();
    __builtin_amdgcn_sched_barrier(0);

    f32x4 sacc[2][4] = {};
    __builtin_amdgcn_s_setprio(1);
#pragma unroll
    for (int tt = 0; tt < 4; ++tt) {
      const int krow = tt * 16 + r15;
#pragma unroll
      for (int kc = 0; kc < 4; ++kc) {
        bf16x8 kf = *(const bf16x8*)((const char*)Ks[cur] + krow * 256 +
                                     (((kc * 4 + g) ^ sw) << 4));
        sacc[0][tt] = __builtin_amdgcn_mfma_f32_16x16x32_bf16(kf, qf[0][kc], sacc[0][tt], 0, 0, 0);
        sacc[1][tt] = __builtin_amdgcn_mfma_f32_16x16x32_bf16(kf, qf[1][kc], sacc[1][tt], 0, 0, 0);
      }
    }
    __builtin_amdgcn_s_setprio(0);

    // fixed-shift softmax: no cross-lane ops, no branches
    u32 pk[2][4][2];
#pragma unroll
    for (int s = 0; s < 2; ++s) {
      float rs = 0.f;
#pragma unroll
      for (int tt = 0; tt < 4; ++tt)
#pragma unroll
        for (int w = 0; w < 2; ++w) {
          float p0 = __builtin_amdgcn_exp2f(sacc[s][tt][2 * w] - M0);
          float p1 = __builtin_amdgcn_exp2f(sacc[s][tt][2 * w + 1] - M0);
          rs += p0 + p1;
          pk[s][tt][w] = cvtpk_bf16(p0, p1);
        }
      l[s] += rs;
    }

    __builtin_amdgcn_s_setprio(1);
#pragma unroll
    for (int dt = 0; dt < 8; ++dt) {
      const int d = dt * 16 + r15;
      const char* vrow = (const char*)Vs[cur] + d * 128;
      const int vsw = d & 7;
#pragma unroll
      for (int kh = 0; kh < 2; ++kh) {
        union { u32 u4[4]; bf16x8 v; } af, b0, b1;
        af.v = *(const bf16x8*)(vrow + (((4 * kh + g) ^ vsw) << 4));
        b0.u4[0] = pk[0][2 * kh][0];     b0.u4[1] = pk[0][2 * kh][1];
        b0.u4[2] = pk[0][2 * kh + 1][0]; b0.u4[3] = pk[0][2 * kh + 1][1];
        b1.u4[0] = pk[1][2 * kh][0];     b1.u4[1] = pk[1][2 * kh][1];
        b1.u4[2] = pk[1][2 * kh + 1][0]; b1.u4[3] = pk[1][2 * kh + 1][1];
        oacc[0][dt] = __builtin_amdgcn_mfma_f32_16x16x32_bf16(af.v, b0.v, oacc[0][dt], 0, 0, 0);
        oacc[1][dt] = __builtin_amdgcn_mfma_f32_16x16x32_bf16(af.v, b1.v, oacc[1][dt], 0, 0, 0);
      }
    }
    __builtin_amdgcn_s_setprio(0);

    __builtin_amdgcn_s_barrier();              // all waves done with buf[cur]
  }

  // epilogue: combine the 4 per-lane l partials once, then normalize and store
#pragma unroll
  for (int s = 0; s < 2; ++s) {
    float lt = l[s] + __shfl_xor(l[s], 16);
    lt += __shfl_xor(lt, 32);
    const float inv = 1.0f / lt;
    u16* Ob = O + ((size_t)(b * 2048 + qrow0 + s * 16)) * 2048 + h * 128;
#pragma unroll
    for (int dt = 0; dt < 8; ++dt) {
      u32x2 pair;
      pair[0] = cvtpk_bf16(oacc[s][dt][0] * inv, oacc[s][dt][1] * inv);
      pair[1] = cvtpk_bf16(oacc[s][dt][2] * inv, oacc[s][dt][3] * inv);
      *(u32x2*)(Ob + dt * 16 + 4 * g) = pair;
    }
  }
}

// ---------------- host ----------------
extern "C" void kernel_launch(void* const* d_in, const int* in_sizes, int n_in,
                              void* d_out, int out_size, void* d_ws, size_t ws_size,
                              hipStream_t stream) {
  const float* x  = (const float*)d_in[0];
  const float* Wq = (const float*)d_in[1];
  const float* Wk = (const float*)d_in[2];
  const float* Wv = (const float*)d_in[3];
  const float* Wo = (const float*)d_in[4];
  const float* bo = (const float*)d_in[5];
  float* out = (float*)d_out;

  char* ws = (char*)d_ws;
  u16* xb    = (u16*)ws;                               // 16 MiB (reused as attn O)
  u16* WqkvT = (u16*)(ws + (size_t)16 * 1024 * 1024);  // 24 MiB [6144][2048]
  u16* WoT   = (u16*)(ws + (size_t)40 * 1024 * 1024);  // 8 MiB  [2048][2048]
  u16* QK    = (u16*)(ws + (size_t)48 * 1024 * 1024);  // 32 MiB [4096][4096]
  u16* VtG   = (u16*)(ws + (size_t)80 * 1024 * 1024);  // 16 MiB [2048][4096]
  u16* Oattn = xb;

  const float C2 = 0.12753102f;   // (1/sqrt(128)) * log2(e), folded into Wk

  cast_x_kernel<<<4096, 256, 0, stream>>>(x, xb);

  TC4 p;
  p.W[0] = Wq; p.W[1] = Wk; p.W[2] = Wv; p.W[3] = Wo;
  p.D[0] = WqkvT;
  p.D[1] = WqkvT + (size_t)2048 * 2048;
  p.D[2] = WqkvT + (size_t)4096 * 2048;
  p.D[3] = WoT;
  p.s[0] = 1.0f; p.s[1] = C2; p.s[2] = 1.0f; p.s[3] = 1.0f;
  transcast4<<<dim3(64, 64, 4), dim3(32, 8), 0, stream>>>(p);

  // QK = xb @ [Wq|Wk_scaled]   (M=4096, N=4096, K=2048), 256x256 tiles, 256 wgs
  gemm256<0, 0, 256, 256, 2, 4><<<dim3(16, 16), 512, 0, stream>>>(
      xb, WqkvT, nullptr, QK, nullptr, 4096, 4096, 2048, 2048, 2048, 4096);
  // V^T = Wv^T @ x^T    (M=2048, N=4096, K=2048), 128x256 tiles, kv tau-permuted
  gemm256<0, 1, 128, 256, 2, 4><<<dim3(16, 16), 512, 0, stream>>>(
      WqkvT + (size_t)4096 * 2048, xb, nullptr, VtG, nullptr,
      2048, 4096, 2048, 2048, 2048, 4096);
  // attention: 128 q-rows per block, 512 blocks of 256 threads (2 strips/wave)
  attn_kernel<<<dim3(16, 16, 2), 256, 0, stream>>>(QK, VtG, Oattn);
  // out = O @ Wo + bo   (M=4096, N=2048, K=2048), 256x128 tiles, 256 wgs
  gemm256<1, 0, 256, 128, 4, 2><<<dim3(16, 16), 512, 0, stream>>>(
      Oattn, WoT, out, nullptr, bo, 4096, 2048, 2048, 2048, 2048, 2048);
}